// Round 4
// baseline (1828.914 us; speedup 1.0000x reference)
//
#include <hip/hip_runtime.h>
#include <math.h>

typedef _Float16 f16;
typedef _Float16 f16x8 __attribute__((ext_vector_type(8)));
typedef float    f32x4 __attribute__((ext_vector_type(4)));
typedef unsigned int u32;
typedef unsigned long long u64;

#define NHEADS 128
#define KLEN   8192
#define DDIM   128
#define SDIM   256
#define SCALE  1.2533141373155003f   // sqrt(pi/2)
#define TAU    5e-4f                 // suspect threshold (f16x3 emul err ~1e-5)

// ---- workspace layout (within proven 34MB) ----
// [0, 1MiB)            : qs16  f16 [128 heads][16 q][256 s]
// [1MiB, +64KiB)       : Gh_t  f16 [256 s][128 d]
// [+64K, +128K)        : Gl_t  f16 [256 s][128 d]  (lo * 4096)
// [1.5MiB)             : u32 suspect counter
// [2MiB, 2MiB+32MiB)   : packed sign bits, u32[128*8192][8]
// suspect LIST lives in d_out (dead until est_kernel, which runs last).
#define QS_OFF     0
#define GH_OFF     (1u << 20)
#define GL_OFF     ((1u << 20) + (64u << 10))
#define CNT_OFF    ((3u << 20) >> 1)             // 1.5 MiB
#define PACKED_OFF (2u << 20)

// ------------------------------------------------------------------
// Sequential f32 dot, d-ascending, single-rounding FMA per step —
// bitwise-matches the numpy reference path (validated round 3).
__device__ __forceinline__ float seq_dot_np(const float* __restrict__ a,
                                            const float* __restrict__ bcol) {
  float acc = 0.0f;
  #pragma unroll 8
  for (int d = 0; d < DDIM; ++d)
    acc = __builtin_fmaf(a[d], bcol[(size_t)d * SDIM], acc);
  return acc;
}

__global__ void zero_cnt_kernel(u32* cnt) { *cnt = 0u; }

// ------------------------------------------------------------------
// prep: q_sketch = q @ G  (f32 accumulate, store f16)
__global__ void prep_qs_kernel(const float* __restrict__ q,
                               const float* __restrict__ G,
                               f16* __restrict__ qs16) {
  int idx = blockIdx.x * 256 + threadIdx.x;      // 128*16*256 = 524288
  int s  = idx & 255;
  int hq = idx >> 8;
  const float* qr = q + (size_t)hq * DDIM;
  float acc = 0.f;
  #pragma unroll 8
  for (int d = 0; d < DDIM; ++d) acc += qr[d] * G[d * SDIM + s];
  qs16[idx] = (f16)acc;
}

// prep: split G into f16 hi + f16 (lo*4096), transposed to [s][d]
__global__ void prep_g_kernel(const float* __restrict__ G,
                              f16* __restrict__ gh, f16* __restrict__ gl) {
  int idx = blockIdx.x * 256 + threadIdx.x;      // 32768
  int d = idx & 127;
  int s = idx >> 7;
  float g = G[d * SDIM + s];
  f16 h = (f16)g;
  gh[s * DDIM + d] = h;
  gl[s * DDIM + d] = (f16)((g - (float)h) * 4096.0f);
}

// ------------------------------------------------------------------
// Pass A: proj = k @ G via f16x3 MFMA; pack sign bits; append suspects
// (|p| < TAU) to list for the out-of-line fixup pass. No heavy code in
// the hot loop -> small I-footprint, low VGPR, high occupancy.
__launch_bounds__(256)
__global__ void proj_sign_kernel(const float* __restrict__ kmat,
                                 const f16* __restrict__ gh,
                                 const f16* __restrict__ gl,
                                 u32* __restrict__ packed,
                                 u32* __restrict__ cnt,
                                 u32* __restrict__ list,
                                 u32 list_cap) {
  __shared__ __align__(16) char smem[32768];     // 16KB Gh phase + 16KB Gl phase

  const int tid  = threadIdx.x;
  const int lane = tid & 63;
  const int w    = tid >> 6;
  const int wg   = blockIdx.x;
  const int head   = wg >> 6;
  const int kchunk = (wg & 63) * 128;
  const int wavebase = kchunk + w * 32;
  const int g4 = lane >> 4;
  const int ln = lane & 15;

  // ---- A fragments for 32 rows (2 blocks of 16), hi/lo f16 split ----
  f16x8 Ah[2][4], Al[2][4];
  #pragma unroll
  for (int rb = 0; rb < 2; ++rb) {
    int row = wavebase + rb * 16 + ln;
    const float* kr = kmat + (size_t)(head * KLEN + row) * DDIM;
    #pragma unroll
    for (int c = 0; c < 4; ++c) {
      const float* p0 = kr + c * 32 + g4 * 8;
      float4 a0 = *(const float4*)p0;
      float4 a1 = *(const float4*)(p0 + 4);
      float af[8] = {a0.x, a0.y, a0.z, a0.w, a1.x, a1.y, a1.z, a1.w};
      f16x8 hh, ll;
      #pragma unroll
      for (int j = 0; j < 8; ++j) {
        f16 h = (f16)af[j];
        hh[j] = h;
        ll[j] = (f16)((af[j] - (float)h) * 4096.0f);
      }
      Ah[rb][c] = hh;
      Al[rb][c] = ll;
    }
  }

  for (int ph = 0; ph < 4; ++ph) {
    __syncthreads();
    {   // stage 64-s phase of Gh/Gl, XOR-swizzled: byte ^= (row&7)<<4
      int sl = tid >> 2;
      int dp = (tid & 3) * 32;
      int sg = ph * 64 + sl;
      const f16* sh  = gh + (size_t)sg * DDIM + dp;
      const f16* slo = gl + (size_t)sg * DDIM + dp;
      #pragma unroll
      for (int i = 0; i < 4; ++i) {
        f16x8 vh = *(const f16x8*)(sh  + i * 8);
        f16x8 vl = *(const f16x8*)(slo + i * 8);
        int off = (sl * 256 + (dp + i * 8) * 2) ^ ((sl & 7) << 4);
        *(f16x8*)(smem + off)         = vh;
        *(f16x8*)(smem + 16384 + off) = vl;
      }
    }
    __syncthreads();

    u32 pw[2][2] = {{0u, 0u}, {0u, 0u}};

    #pragma unroll
    for (int tl = 0; tl < 4; ++tl) {
      const int sl = tl * 16 + ln;
      f16x8 Bh[4], Bl[4];
      #pragma unroll
      for (int c = 0; c < 4; ++c) {
        int off = (sl * 256 + c * 64 + g4 * 16) ^ ((sl & 7) << 4);
        Bh[c] = *(const f16x8*)(smem + off);
        Bl[c] = *(const f16x8*)(smem + 16384 + off);
      }
      f32x4 ah0 = {0,0,0,0}, al0 = {0,0,0,0};
      f32x4 ah1 = {0,0,0,0}, al1 = {0,0,0,0};
      #pragma unroll
      for (int c = 0; c < 4; ++c) {
        ah0 = __builtin_amdgcn_mfma_f32_16x16x32_f16(Ah[0][c], Bh[c], ah0, 0, 0, 0);
        al0 = __builtin_amdgcn_mfma_f32_16x16x32_f16(Ah[0][c], Bl[c], al0, 0, 0, 0);
        al0 = __builtin_amdgcn_mfma_f32_16x16x32_f16(Al[0][c], Bh[c], al0, 0, 0, 0);
        ah1 = __builtin_amdgcn_mfma_f32_16x16x32_f16(Ah[1][c], Bh[c], ah1, 0, 0, 0);
        al1 = __builtin_amdgcn_mfma_f32_16x16x32_f16(Ah[1][c], Bl[c], al1, 0, 0, 0);
        al1 = __builtin_amdgcn_mfma_f32_16x16x32_f16(Al[1][c], Bh[c], al1, 0, 0, 0);
      }
      float p[2][4];
      #pragma unroll
      for (int r = 0; r < 4; ++r) {
        p[0][r] = ah0[r] + al0[r] * 2.44140625e-4f;   // 1/4096
        p[1][r] = ah1[r] + al1[r] * 2.44140625e-4f;
      }

      // append suspects (rare: ~5.6e-4 per element) for out-of-line fixup
      #pragma unroll
      for (int rb = 0; rb < 2; ++rb) {
        #pragma unroll
        for (int r = 0; r < 4; ++r) {
          if (__builtin_fabsf(p[rb][r]) < TAU) {
            u32 grow = (u32)(head * KLEN + wavebase + rb * 16 + g4 * 4 + r);
            u32 sg   = (u32)(ph * 64 + tl * 16 + ln);
            u32 idx = atomicAdd(cnt, 1u);
            if (idx < list_cap) list[idx] = (grow << 8) | sg;
          }
        }
      }

      // pack sign bits via ballot
      #pragma unroll
      for (int rb = 0; rb < 2; ++rb) {
        u64 b0 = __ballot(p[rb][0] > 0.0f ? 1 : 0);
        u64 b1 = __ballot(p[rb][1] > 0.0f ? 1 : 0);
        u64 b2 = __ballot(p[rb][2] > 0.0f ? 1 : 0);
        u64 b3 = __ballot(p[rb][3] > 0.0f ? 1 : 0);
        if (lane < 16) {
          int r = lane & 3;
          u64 b = (r == 0) ? b0 : (r == 1) ? b1 : (r == 2) ? b2 : b3;
          u32 u = (u32)((b >> (16 * (lane >> 2))) & 0xffffu);
          pw[rb][tl >> 1] |= u << (16 * (tl & 1));
        }
      }
    }

    if (lane < 16) {
      #pragma unroll
      for (int rb = 0; rb < 2; ++rb) {
        int row = wavebase + rb * 16 + lane;
        uint2 v; v.x = pw[rb][0]; v.y = pw[rb][1];
        *(uint2*)(packed + (size_t)(head * KLEN + row) * 8 + ph * 2) = v;
      }
    }
  }
}

// ------------------------------------------------------------------
// Pass B: per suspect, recompute the np-exact sequential FMA dot and
// patch the packed bit atomically. ~150K entries -> tens of µs.
__global__ void fixup_kernel(const float* __restrict__ kmat,
                             const float* __restrict__ G,
                             u32* __restrict__ packed,
                             const u32* __restrict__ cnt,
                             const u32* __restrict__ list,
                             u32 list_cap) {
  u32 n = *cnt;
  if (n > list_cap) n = list_cap;
  int stride = gridDim.x * blockDim.x;
  for (u32 i = blockIdx.x * blockDim.x + threadIdx.x; i < n; i += stride) {
    u32 e = list[i];
    u32 grow = e >> 8;
    u32 s    = e & 255u;
    const float* a = kmat + (size_t)grow * DDIM;
    float acc = seq_dot_np(a, G + s);
    u32* wp = packed + (size_t)grow * 8 + (s >> 5);
    u32 mask = 1u << (s & 31);
    if (acc > 0.0f) atomicOr(wp, mask);
    else            atomicAnd(wp, ~mask);
  }
}

// ------------------------------------------------------------------
// est = q_sketch @ sign^T, bits -> ±1 f16 on the fly, MFMA f16, f32 out
__launch_bounds__(256)
__global__ void est_kernel(const f16* __restrict__ qs16,
                           const u32* __restrict__ packed,
                           float* __restrict__ out) {
  const int tid  = threadIdx.x;
  const int lane = tid & 63;
  const int w    = tid >> 6;
  const int wg   = blockIdx.x;
  const int head   = wg >> 5;
  const int kchunk = (wg & 31) * 256;
  const int g4 = lane >> 4, ln = lane & 15;

  f16x8 aq[8];
  const f16* qb = qs16 + (size_t)head * 16 * SDIM;
  #pragma unroll
  for (int c = 0; c < 8; ++c)
    aq[c] = *(const f16x8*)(qb + ln * SDIM + c * 32 + g4 * 8);

  const int kb = kchunk + w * 64;
  #pragma unroll
  for (int kt = 0; kt < 4; ++kt) {
    int krow = kb + kt * 16 + ln;
    const u32* bp = packed + (size_t)(head * KLEN + krow) * 8;
    uint4 q0 = *(const uint4*)bp;
    uint4 q1 = *(const uint4*)(bp + 4);
    u32 b32[8] = {q0.x, q0.y, q0.z, q0.w, q1.x, q1.y, q1.z, q1.w};
    f32x4 acc = {0, 0, 0, 0};
    #pragma unroll
    for (int c = 0; c < 8; ++c) {
      u32 byte8 = (b32[c] >> (8 * g4)) & 0xffu;
      union { u32 u[4]; f16x8 h; } sv;
      #pragma unroll
      for (int pp = 0; pp < 4; ++pp) {
        u32 v = 0x3C003C00u;
        v |= ((byte8 >> (2 * pp))     & 1u) ? 0u : 0x8000u;
        v |= ((byte8 >> (2 * pp + 1)) & 1u) ? 0u : 0x80000000u;
        sv.u[pp] = v;
      }
      acc = __builtin_amdgcn_mfma_f32_16x16x32_f16(aq[c], sv.h, acc, 0, 0, 0);
    }
    float* ob = out + (size_t)(head * 16) * KLEN + kb + kt * 16 + ln;
    #pragma unroll
    for (int r = 0; r < 4; ++r) {
      int qrow = g4 * 4 + r;
      ob[(size_t)qrow * KLEN] = acc[r] * SCALE;
    }
  }
}

// ------------------------------------------------------------------
extern "C" void kernel_launch(void* const* d_in, const int* in_sizes, int n_in,
                              void* d_out, int out_size, void* d_ws, size_t ws_size,
                              hipStream_t stream) {
  const float* q = (const float*)d_in[0];
  const float* k = (const float*)d_in[1];
  const float* G = (const float*)d_in[2];
  float* out = (float*)d_out;
  char* ws = (char*)d_ws;

  f16* qs16  = (f16*)(ws + QS_OFF);
  f16* gh    = (f16*)(ws + GH_OFF);
  f16* gl    = (f16*)(ws + GL_OFF);
  u32* cnt   = (u32*)(ws + CNT_OFF);
  u32* packed = (u32*)(ws + PACKED_OFF);

  // suspect list lives in d_out: written by proj, read by fixup, then
  // est_kernel fully overwrites d_out (stream-ordered; no race).
  u32* list = (u32*)d_out;
  u32 list_cap = (u32)out_size;   // 16M entries >> expected ~150K

  zero_cnt_kernel<<<1, 1, 0, stream>>>(cnt);
  prep_qs_kernel<<<2048, 256, 0, stream>>>(q, G, qs16);
  prep_g_kernel<<<128, 256, 0, stream>>>(G, gh, gl);
  proj_sign_kernel<<<8192, 256, 0, stream>>>(k, gh, gl, packed, cnt, list, list_cap);
  fixup_kernel<<<256, 256, 0, stream>>>(k, G, packed, cnt, list, list_cap);
  est_kernel<<<4096, 256, 0, stream>>>(qs16, packed, out);
}

// Round 5
// 783.249 us; speedup vs baseline: 2.3350x; 2.3350x over previous
//
#include <hip/hip_runtime.h>
#include <math.h>

typedef _Float16 f16;
typedef _Float16 f16x8 __attribute__((ext_vector_type(8)));
typedef float    f32x4 __attribute__((ext_vector_type(4)));
typedef unsigned int u32;
typedef unsigned long long u64;

#define NHEADS 128
#define KLEN   8192
#define DDIM   128
#define SDIM   256
#define SCALE  1.2533141373155003f   // sqrt(pi/2)
#define TAU    5e-4f                 // suspect threshold (f16x3 emul err ~1e-5)

// ---- workspace layout ----
// [0, 1MiB)            : qs16  f16 [128 heads][16 q][256 s]
// [1MiB, +64KiB)       : Gh_t  f16 [256 s][128 d]
// [+64K, +128K)        : Gl_t  f16 [256 s][128 d]  (lo * 4096)
// [2MiB, 2MiB+32MiB)   : packed sign bits, u32[128*8192][8]
// suspect MASK (u32[1M rows][8], 32MB) lives in d_out (dead until est,
// which runs last and fully overwrites d_out).
#define QS_OFF     0
#define GH_OFF     (1u << 20)
#define GL_OFF     ((1u << 20) + (64u << 10))
#define PACKED_OFF (2u << 20)

// ------------------------------------------------------------------
// Sequential f32 dot, d-ascending, single-rounding FMA per step —
// bitwise-matches the numpy reference path (validated round 3).
__device__ __forceinline__ float seq_dot_np(const float* __restrict__ a,
                                            const float* __restrict__ bcol) {
  float acc = 0.0f;
  #pragma unroll 8
  for (int d = 0; d < DDIM; ++d)
    acc = __builtin_fmaf(a[d], bcol[(size_t)d * SDIM], acc);
  return acc;
}

// ------------------------------------------------------------------
// prep: q_sketch = q @ G  (f32 accumulate, store f16)
__global__ void prep_qs_kernel(const float* __restrict__ q,
                               const float* __restrict__ G,
                               f16* __restrict__ qs16) {
  int idx = blockIdx.x * 256 + threadIdx.x;      // 128*16*256 = 524288
  int s  = idx & 255;
  int hq = idx >> 8;
  const float* qr = q + (size_t)hq * DDIM;
  float acc = 0.f;
  #pragma unroll 8
  for (int d = 0; d < DDIM; ++d) acc += qr[d] * G[d * SDIM + s];
  qs16[idx] = (f16)acc;
}

// prep: split G into f16 hi + f16 (lo*4096), transposed to [s][d]
__global__ void prep_g_kernel(const float* __restrict__ G,
                              f16* __restrict__ gh, f16* __restrict__ gl) {
  int idx = blockIdx.x * 256 + threadIdx.x;      // 32768
  int d = idx & 127;
  int s = idx >> 7;
  float g = G[d * SDIM + s];
  f16 h = (f16)g;
  gh[s * DDIM + d] = h;
  gl[s * DDIM + d] = (f16)((g - (float)h) * 4096.0f);
}

// ------------------------------------------------------------------
// Pass A: proj = k @ G via f16x3 MFMA, B-frags read straight from L1/L2
// (G hi/lo = 128KB, cache-resident). No LDS, no barriers, no atomics.
// Emits packed sign bits + per-row suspect bitmask (|p| < TAU).
// grid: 128 heads * 64 chunks of 128 rows; block 256 = 4 independent waves.
__launch_bounds__(256)
__global__ void proj_sign_kernel(const float* __restrict__ kmat,
                                 const f16* __restrict__ gh,
                                 const f16* __restrict__ gl,
                                 u32* __restrict__ packed,
                                 u32* __restrict__ smask) {
  const int tid  = threadIdx.x;
  const int lane = tid & 63;
  const int w    = tid >> 6;
  const int wg   = blockIdx.x;
  const int head   = wg >> 6;
  const int kchunk = (wg & 63) * 128;
  const int wavebase = kchunk + w * 32;
  const int g4 = lane >> 4;
  const int ln = lane & 15;

  // ---- A fragments for 32 rows (2 blocks of 16), hi/lo f16 split ----
  // A[m][kk]: m = lane&15, kk = 8*(lane>>4)+j
  f16x8 Ah[2][4], Al[2][4];
  #pragma unroll
  for (int rb = 0; rb < 2; ++rb) {
    int row = wavebase + rb * 16 + ln;
    const float* kr = kmat + (size_t)(head * KLEN + row) * DDIM;
    #pragma unroll
    for (int c = 0; c < 4; ++c) {
      const float* p0 = kr + c * 32 + g4 * 8;
      float4 a0 = *(const float4*)p0;
      float4 a1 = *(const float4*)(p0 + 4);
      float af[8] = {a0.x, a0.y, a0.z, a0.w, a1.x, a1.y, a1.z, a1.w};
      f16x8 hh, ll;
      #pragma unroll
      for (int j = 0; j < 8; ++j) {
        f16 h = (f16)af[j];
        hh[j] = h;
        ll[j] = (f16)((af[j] - (float)h) * 4096.0f);
      }
      Ah[rb][c] = hh;
      Al[rb][c] = ll;
    }
  }

  u32 pw[2][8] = {{0}};   // packed sign words  (lane<16: row rb*16+lane)
  u32 sw[2][8] = {{0}};   // suspect mask words

  #pragma unroll
  for (int tl = 0; tl < 16; ++tl) {              // 16 s-tiles of 16
    const int s = tl * 16 + ln;
    // B frags from global: B[kk][n]: n=lane&15 (s), kk=8*(lane>>4)+j (d)
    const f16* bh = gh + (size_t)s * DDIM + g4 * 8;
    const f16* bl = gl + (size_t)s * DDIM + g4 * 8;
    f16x8 Bh[4], Bl[4];
    #pragma unroll
    for (int c = 0; c < 4; ++c) {
      Bh[c] = *(const f16x8*)(bh + c * 32);
      Bl[c] = *(const f16x8*)(bl + c * 32);
    }
    f32x4 ah0 = {0,0,0,0}, al0 = {0,0,0,0};
    f32x4 ah1 = {0,0,0,0}, al1 = {0,0,0,0};
    #pragma unroll
    for (int c = 0; c < 4; ++c) {
      ah0 = __builtin_amdgcn_mfma_f32_16x16x32_f16(Ah[0][c], Bh[c], ah0, 0, 0, 0);
      al0 = __builtin_amdgcn_mfma_f32_16x16x32_f16(Ah[0][c], Bl[c], al0, 0, 0, 0);
      al0 = __builtin_amdgcn_mfma_f32_16x16x32_f16(Al[0][c], Bh[c], al0, 0, 0, 0);
      ah1 = __builtin_amdgcn_mfma_f32_16x16x32_f16(Ah[1][c], Bh[c], ah1, 0, 0, 0);
      al1 = __builtin_amdgcn_mfma_f32_16x16x32_f16(Ah[1][c], Bl[c], al1, 0, 0, 0);
      al1 = __builtin_amdgcn_mfma_f32_16x16x32_f16(Al[1][c], Bh[c], al1, 0, 0, 0);
    }
    float p[2][4];
    #pragma unroll
    for (int r = 0; r < 4; ++r) {
      p[0][r] = ah0[r] + al0[r] * 2.44140625e-4f;   // 1/4096
      p[1][r] = ah1[r] + al1[r] * 2.44140625e-4f;
    }

    // ballot-pack sign bits and suspect bits
    #pragma unroll
    for (int rb = 0; rb < 2; ++rb) {
      u64 b0 = __ballot(p[rb][0] > 0.0f ? 1 : 0);
      u64 b1 = __ballot(p[rb][1] > 0.0f ? 1 : 0);
      u64 b2 = __ballot(p[rb][2] > 0.0f ? 1 : 0);
      u64 b3 = __ballot(p[rb][3] > 0.0f ? 1 : 0);
      u64 t0 = __ballot(__builtin_fabsf(p[rb][0]) < TAU ? 1 : 0);
      u64 t1 = __ballot(__builtin_fabsf(p[rb][1]) < TAU ? 1 : 0);
      u64 t2 = __ballot(__builtin_fabsf(p[rb][2]) < TAU ? 1 : 0);
      u64 t3 = __ballot(__builtin_fabsf(p[rb][3]) < TAU ? 1 : 0);
      if (lane < 16) {
        int r = lane & 3;
        u64 b = (r == 0) ? b0 : (r == 1) ? b1 : (r == 2) ? b2 : b3;
        u64 t = (r == 0) ? t0 : (r == 1) ? t1 : (r == 2) ? t2 : t3;
        u32 sh = 16u * (u32)(lane >> 2);
        u32 ub = (u32)((b >> sh) & 0xffffu);
        u32 ut = (u32)((t >> sh) & 0xffffu);
        pw[rb][tl >> 1] |= ub << (16 * (tl & 1));
        sw[rb][tl >> 1] |= ut << (16 * (tl & 1));
      }
    }
  }

  if (lane < 16) {
    #pragma unroll
    for (int rb = 0; rb < 2; ++rb) {
      size_t row = (size_t)(head * KLEN + wavebase + rb * 16 + lane);
      uint4 v0, v1, m0, m1;
      v0.x = pw[rb][0]; v0.y = pw[rb][1]; v0.z = pw[rb][2]; v0.w = pw[rb][3];
      v1.x = pw[rb][4]; v1.y = pw[rb][5]; v1.z = pw[rb][6]; v1.w = pw[rb][7];
      m0.x = sw[rb][0]; m0.y = sw[rb][1]; m0.z = sw[rb][2]; m0.w = sw[rb][3];
      m1.x = sw[rb][4]; m1.y = sw[rb][5]; m1.z = sw[rb][6]; m1.w = sw[rb][7];
      *(uint4*)(packed + row * 8)     = v0;
      *(uint4*)(packed + row * 8 + 4) = v1;
      *(uint4*)(smask  + row * 8)     = m0;
      *(uint4*)(smask  + row * 8 + 4) = m1;
    }
  }
}

// ------------------------------------------------------------------
// Pass B: one thread per k-row. Read 32B suspect mask; for each flagged
// s recompute the np-exact seq-FMA dot and patch the bit (row-exclusive,
// no atomics).
__global__ void fixup_kernel(const float* __restrict__ kmat,
                             const float* __restrict__ G,
                             u32* __restrict__ packed,
                             const u32* __restrict__ smask) {
  int row = blockIdx.x * 256 + threadIdx.x;      // 1,048,576 rows
  if (row >= NHEADS * KLEN) return;
  const u32* mp = smask + (size_t)row * 8;
  uint4 m0 = *(const uint4*)mp;
  uint4 m1 = *(const uint4*)(mp + 4);
  u32 mw[8] = {m0.x, m0.y, m0.z, m0.w, m1.x, m1.y, m1.z, m1.w};
  if (!(mw[0] | mw[1] | mw[2] | mw[3] | mw[4] | mw[5] | mw[6] | mw[7])) return;
  const float* a = kmat + (size_t)row * DDIM;
  #pragma unroll
  for (int wd = 0; wd < 8; ++wd) {
    u32 m = mw[wd];
    if (!m) continue;
    u32 pk = packed[(size_t)row * 8 + wd];
    while (m) {
      int b = __ffs(m) - 1;  m &= m - 1;
      int s = wd * 32 + b;
      float acc = seq_dot_np(a, G + s);
      if (acc > 0.0f) pk |= (1u << b);
      else            pk &= ~(1u << b);
    }
    packed[(size_t)row * 8 + wd] = pk;
  }
}

// ------------------------------------------------------------------
// est = q_sketch @ sign^T, bits -> ±1 f16 on the fly, MFMA f16, f32 out
__launch_bounds__(256)
__global__ void est_kernel(const f16* __restrict__ qs16,
                           const u32* __restrict__ packed,
                           float* __restrict__ out) {
  const int tid  = threadIdx.x;
  const int lane = tid & 63;
  const int w    = tid >> 6;
  const int wg   = blockIdx.x;
  const int head   = wg >> 5;
  const int kchunk = (wg & 31) * 256;
  const int g4 = lane >> 4, ln = lane & 15;

  f16x8 aq[8];
  const f16* qb = qs16 + (size_t)head * 16 * SDIM;
  #pragma unroll
  for (int c = 0; c < 8; ++c)
    aq[c] = *(const f16x8*)(qb + ln * SDIM + c * 32 + g4 * 8);

  const int kb = kchunk + w * 64;
  #pragma unroll
  for (int kt = 0; kt < 4; ++kt) {
    int krow = kb + kt * 16 + ln;
    const u32* bp = packed + (size_t)(head * KLEN + krow) * 8;
    uint4 q0 = *(const uint4*)bp;
    uint4 q1 = *(const uint4*)(bp + 4);
    u32 b32[8] = {q0.x, q0.y, q0.z, q0.w, q1.x, q1.y, q1.z, q1.w};
    f32x4 acc = {0, 0, 0, 0};
    #pragma unroll
    for (int c = 0; c < 8; ++c) {
      u32 byte8 = (b32[c] >> (8 * g4)) & 0xffu;
      union { u32 u[4]; f16x8 h; } sv;
      #pragma unroll
      for (int pp = 0; pp < 4; ++pp) {
        u32 v = 0x3C003C00u;
        v |= ((byte8 >> (2 * pp))     & 1u) ? 0u : 0x8000u;
        v |= ((byte8 >> (2 * pp + 1)) & 1u) ? 0u : 0x80000000u;
        sv.u[pp] = v;
      }
      acc = __builtin_amdgcn_mfma_f32_16x16x32_f16(aq[c], sv.h, acc, 0, 0, 0);
    }
    float* ob = out + (size_t)(head * 16) * KLEN + kb + kt * 16 + ln;
    #pragma unroll
    for (int r = 0; r < 4; ++r) {
      int qrow = g4 * 4 + r;
      ob[(size_t)qrow * KLEN] = acc[r] * SCALE;
    }
  }
}

// ------------------------------------------------------------------
extern "C" void kernel_launch(void* const* d_in, const int* in_sizes, int n_in,
                              void* d_out, int out_size, void* d_ws, size_t ws_size,
                              hipStream_t stream) {
  const float* q = (const float*)d_in[0];
  const float* k = (const float*)d_in[1];
  const float* G = (const float*)d_in[2];
  float* out = (float*)d_out;
  char* ws = (char*)d_ws;

  f16* qs16   = (f16*)(ws + QS_OFF);
  f16* gh     = (f16*)(ws + GH_OFF);
  f16* gl     = (f16*)(ws + GL_OFF);
  u32* packed = (u32*)(ws + PACKED_OFF);

  // suspect mask in d_out (8M u32 = 32MB << out_size u32s); fully written
  // by proj_sign before fixup reads it; est overwrites d_out afterwards.
  u32* smask = (u32*)d_out;

  prep_qs_kernel<<<2048, 256, 0, stream>>>(q, G, qs16);
  prep_g_kernel<<<128, 256, 0, stream>>>(G, gh, gl);
  proj_sign_kernel<<<8192, 256, 0, stream>>>(k, gh, gl, packed, smask);
  fixup_kernel<<<4096, 256, 0, stream>>>(k, G, packed, smask);
  est_kernel<<<4096, 256, 0, stream>>>(qs16, packed, out);
}

// Round 6
// 783.106 us; speedup vs baseline: 2.3355x; 1.0002x over previous
//
#include <hip/hip_runtime.h>
#include <math.h>

typedef _Float16 f16;
typedef _Float16 f16x8 __attribute__((ext_vector_type(8)));
typedef float    f32x4 __attribute__((ext_vector_type(4)));
typedef unsigned int u32;
typedef unsigned long long u64;

#define NHEADS 128
#define KLEN   8192
#define DDIM   128
#define SDIM   256
#define SCALE  1.2533141373155003f   // sqrt(pi/2)
#define TAU    3e-3f                 // suspect threshold; sigma(err) ~2.2e-4 -> 13.6 sigma

// ---- workspace layout ----
// [0, 1MiB)                : qs16 f16 [128 heads][16 q][256 s]
// [1MiB, +64KiB)           : Gh_t f16 [256 s][128 d]   (hi part, transposed)
// [1MiB+64K, +128KiB)      : Gt   f32 [256 s][128 d]   (exact G, transposed)
// [2MiB, 2MiB+32MiB)       : packed sign bits, u32[128*8192][8]
// suspect MASK (u32[1M rows][8], 32MB) lives in d_out (dead until est).
#define QS_OFF     0
#define GH_OFF     (1u << 20)
#define GT_OFF     ((1u << 20) + (64u << 10))
#define PACKED_OFF (2u << 20)

// ------------------------------------------------------------------
// Sequential f32 dot, d-ascending, single-rounding FMA per step —
// bitwise-matches the numpy reference path (validated round 3).
// Reads the TRANSPOSED exact copy of G (contiguous column) — same f32
// values, same order -> same bits.
__device__ __forceinline__ float seq_dot_np(const float* __restrict__ a,
                                            const float* __restrict__ gcol) {
  float acc = 0.0f;
  #pragma unroll 8
  for (int d = 0; d < DDIM; ++d)
    acc = __builtin_fmaf(a[d], gcol[d], acc);
  return acc;
}

// ------------------------------------------------------------------
// prep: q_sketch = q @ G  (f32 accumulate, store f16)
__global__ void prep_qs_kernel(const float* __restrict__ q,
                               const float* __restrict__ G,
                               f16* __restrict__ qs16) {
  int idx = blockIdx.x * 256 + threadIdx.x;      // 128*16*256 = 524288
  int s  = idx & 255;
  int hq = idx >> 8;
  const float* qr = q + (size_t)hq * DDIM;
  float acc = 0.f;
  #pragma unroll 8
  for (int d = 0; d < DDIM; ++d) acc += qr[d] * G[d * SDIM + s];
  qs16[idx] = (f16)acc;
}

// prep: G -> f16 transposed (hi) + f32 transposed exact copy
__global__ void prep_g_kernel(const float* __restrict__ G,
                              f16* __restrict__ gh, float* __restrict__ gt) {
  int idx = blockIdx.x * 256 + threadIdx.x;      // 32768
  int d = idx & 127;
  int s = idx >> 7;
  float g = G[d * SDIM + s];
  gh[s * DDIM + d] = (f16)g;
  gt[s * DDIM + d] = g;
}

// ------------------------------------------------------------------
// Pass A: proj ~= f16(k) @ f16(G) via single MFMA per acc chain.
// B-frags straight from L1/L2 (Gh = 64KB, cache-resident). No LDS, no
// barriers, no atomics. Emits packed sign bits + per-row suspect mask.
// grid: 128 heads * 64 chunks of 128 rows; block 256 = 4 independent waves.
__launch_bounds__(256)
__global__ void proj_sign_kernel(const float* __restrict__ kmat,
                                 const f16* __restrict__ gh,
                                 u32* __restrict__ packed,
                                 u32* __restrict__ smask) {
  const int tid  = threadIdx.x;
  const int lane = tid & 63;
  const int w    = tid >> 6;
  const int wg   = blockIdx.x;
  const int head   = wg >> 6;
  const int kchunk = (wg & 63) * 128;
  const int wavebase = kchunk + w * 32;
  const int g4 = lane >> 4;
  const int ln = lane & 15;

  // ---- A fragments (hi only) for 32 rows (2 blocks of 16) ----
  // A[m][kk]: m = lane&15, kk = 8*(lane>>4)+j
  f16x8 Ah[2][4];
  #pragma unroll
  for (int rb = 0; rb < 2; ++rb) {
    int row = wavebase + rb * 16 + ln;
    const float* kr = kmat + (size_t)(head * KLEN + row) * DDIM;
    #pragma unroll
    for (int c = 0; c < 4; ++c) {
      const float* p0 = kr + c * 32 + g4 * 8;
      float4 a0 = *(const float4*)p0;
      float4 a1 = *(const float4*)(p0 + 4);
      f16x8 hh;
      hh[0] = (f16)a0.x; hh[1] = (f16)a0.y; hh[2] = (f16)a0.z; hh[3] = (f16)a0.w;
      hh[4] = (f16)a1.x; hh[5] = (f16)a1.y; hh[6] = (f16)a1.z; hh[7] = (f16)a1.w;
      Ah[rb][c] = hh;
    }
  }

  u32 pw[2][8] = {{0}};   // packed sign words  (lane<16: row rb*16+lane)
  u32 sw[2][8] = {{0}};   // suspect mask words

  #pragma unroll
  for (int tl = 0; tl < 16; ++tl) {              // 16 s-tiles of 16
    const int s = tl * 16 + ln;
    const f16* bh = gh + (size_t)s * DDIM + g4 * 8;
    f16x8 Bh[4];
    #pragma unroll
    for (int c = 0; c < 4; ++c) Bh[c] = *(const f16x8*)(bh + c * 32);

    f32x4 p0 = {0,0,0,0}, p1 = {0,0,0,0};
    #pragma unroll
    for (int c = 0; c < 4; ++c) {
      p0 = __builtin_amdgcn_mfma_f32_16x16x32_f16(Ah[0][c], Bh[c], p0, 0, 0, 0);
      p1 = __builtin_amdgcn_mfma_f32_16x16x32_f16(Ah[1][c], Bh[c], p1, 0, 0, 0);
    }
    float p[2][4] = {{p0[0], p0[1], p0[2], p0[3]},
                     {p1[0], p1[1], p1[2], p1[3]}};

    // ---- sign ballots ----
    #pragma unroll
    for (int rb = 0; rb < 2; ++rb) {
      u64 b0 = __ballot(p[rb][0] > 0.0f ? 1 : 0);
      u64 b1 = __ballot(p[rb][1] > 0.0f ? 1 : 0);
      u64 b2 = __ballot(p[rb][2] > 0.0f ? 1 : 0);
      u64 b3 = __ballot(p[rb][3] > 0.0f ? 1 : 0);
      if (lane < 16) {
        int r = lane & 3;
        u64 b = (r == 0) ? b0 : (r == 1) ? b1 : (r == 2) ? b2 : b3;
        u32 sh = 16u * (u32)(lane >> 2);
        pw[rb][tl >> 1] |= ((u32)((b >> sh) & 0xffffu)) << (16 * (tl & 1));
      }
    }

    // ---- suspect ballots, guarded (rare: ~30% of tiles trip) ----
    float mn = fminf(
        fminf(fminf(__builtin_fabsf(p[0][0]), __builtin_fabsf(p[0][1])),
              fminf(__builtin_fabsf(p[0][2]), __builtin_fabsf(p[0][3]))),
        fminf(fminf(__builtin_fabsf(p[1][0]), __builtin_fabsf(p[1][1])),
              fminf(__builtin_fabsf(p[1][2]), __builtin_fabsf(p[1][3]))));
    if (__any(mn < TAU ? 1 : 0)) {
      #pragma unroll
      for (int rb = 0; rb < 2; ++rb) {
        u64 t0 = __ballot(__builtin_fabsf(p[rb][0]) < TAU ? 1 : 0);
        u64 t1 = __ballot(__builtin_fabsf(p[rb][1]) < TAU ? 1 : 0);
        u64 t2 = __ballot(__builtin_fabsf(p[rb][2]) < TAU ? 1 : 0);
        u64 t3 = __ballot(__builtin_fabsf(p[rb][3]) < TAU ? 1 : 0);
        if (lane < 16) {
          int r = lane & 3;
          u64 t = (r == 0) ? t0 : (r == 1) ? t1 : (r == 2) ? t2 : t3;
          u32 sh = 16u * (u32)(lane >> 2);
          sw[rb][tl >> 1] |= ((u32)((t >> sh) & 0xffffu)) << (16 * (tl & 1));
        }
      }
    }
  }

  if (lane < 16) {
    #pragma unroll
    for (int rb = 0; rb < 2; ++rb) {
      size_t row = (size_t)(head * KLEN + wavebase + rb * 16 + lane);
      uint4 v0, v1, m0, m1;
      v0.x = pw[rb][0]; v0.y = pw[rb][1]; v0.z = pw[rb][2]; v0.w = pw[rb][3];
      v1.x = pw[rb][4]; v1.y = pw[rb][5]; v1.z = pw[rb][6]; v1.w = pw[rb][7];
      m0.x = sw[rb][0]; m0.y = sw[rb][1]; m0.z = sw[rb][2]; m0.w = sw[rb][3];
      m1.x = sw[rb][4]; m1.y = sw[rb][5]; m1.z = sw[rb][6]; m1.w = sw[rb][7];
      *(uint4*)(packed + row * 8)     = v0;
      *(uint4*)(packed + row * 8 + 4) = v1;
      *(uint4*)(smask  + row * 8)     = m0;
      *(uint4*)(smask  + row * 8 + 4) = m1;
    }
  }
}

// ------------------------------------------------------------------
// Pass B: one thread per k-row. For each flagged s recompute the
// np-exact seq-FMA dot (contiguous Gt column) and patch the bit
// (row-exclusive, no atomics).
__global__ void fixup_kernel(const float* __restrict__ kmat,
                             const float* __restrict__ gt,
                             u32* __restrict__ packed,
                             const u32* __restrict__ smask) {
  int row = blockIdx.x * 256 + threadIdx.x;      // 1,048,576 rows
  if (row >= NHEADS * KLEN) return;
  const u32* mp = smask + (size_t)row * 8;
  uint4 m0 = *(const uint4*)mp;
  uint4 m1 = *(const uint4*)(mp + 4);
  u32 mw[8] = {m0.x, m0.y, m0.z, m0.w, m1.x, m1.y, m1.z, m1.w};
  if (!(mw[0] | mw[1] | mw[2] | mw[3] | mw[4] | mw[5] | mw[6] | mw[7])) return;
  const float* a = kmat + (size_t)row * DDIM;
  #pragma unroll
  for (int wd = 0; wd < 8; ++wd) {
    u32 m = mw[wd];
    if (!m) continue;
    u32 pk = packed[(size_t)row * 8 + wd];
    while (m) {
      int b = __ffs(m) - 1;  m &= m - 1;
      int s = wd * 32 + b;
      float acc = seq_dot_np(a, gt + (size_t)s * DDIM);
      if (acc > 0.0f) pk |= (1u << b);
      else            pk &= ~(1u << b);
    }
    packed[(size_t)row * 8 + wd] = pk;
  }
}

// ------------------------------------------------------------------
// est = q_sketch @ sign^T, bits -> ±1 f16 on the fly, MFMA f16, f32 out
__launch_bounds__(256)
__global__ void est_kernel(const f16* __restrict__ qs16,
                           const u32* __restrict__ packed,
                           float* __restrict__ out) {
  const int tid  = threadIdx.x;
  const int lane = tid & 63;
  const int w    = tid >> 6;
  const int wg   = blockIdx.x;
  const int head   = wg >> 5;
  const int kchunk = (wg & 31) * 256;
  const int g4 = lane >> 4, ln = lane & 15;

  f16x8 aq[8];
  const f16* qb = qs16 + (size_t)head * 16 * SDIM;
  #pragma unroll
  for (int c = 0; c < 8; ++c)
    aq[c] = *(const f16x8*)(qb + ln * SDIM + c * 32 + g4 * 8);

  const int kb = kchunk + w * 64;
  #pragma unroll
  for (int kt = 0; kt < 4; ++kt) {
    int krow = kb + kt * 16 + ln;
    const u32* bp = packed + (size_t)(head * KLEN + krow) * 8;
    uint4 q0 = *(const uint4*)bp;
    uint4 q1 = *(const uint4*)(bp + 4);
    u32 b32[8] = {q0.x, q0.y, q0.z, q0.w, q1.x, q1.y, q1.z, q1.w};
    f32x4 acc = {0, 0, 0, 0};
    #pragma unroll
    for (int c = 0; c < 8; ++c) {
      u32 byte8 = (b32[c] >> (8 * g4)) & 0xffu;
      union { u32 u[4]; f16x8 h; } sv;
      #pragma unroll
      for (int pp = 0; pp < 4; ++pp) {
        u32 v = 0x3C003C00u;
        v |= ((byte8 >> (2 * pp))     & 1u) ? 0u : 0x8000u;
        v |= ((byte8 >> (2 * pp + 1)) & 1u) ? 0u : 0x80000000u;
        sv.u[pp] = v;
      }
      acc = __builtin_amdgcn_mfma_f32_16x16x32_f16(aq[c], sv.h, acc, 0, 0, 0);
    }
    float* ob = out + (size_t)(head * 16) * KLEN + kb + kt * 16 + ln;
    #pragma unroll
    for (int r = 0; r < 4; ++r) {
      int qrow = g4 * 4 + r;
      ob[(size_t)qrow * KLEN] = acc[r] * SCALE;
    }
  }
}

// ------------------------------------------------------------------
extern "C" void kernel_launch(void* const* d_in, const int* in_sizes, int n_in,
                              void* d_out, int out_size, void* d_ws, size_t ws_size,
                              hipStream_t stream) {
  const float* q = (const float*)d_in[0];
  const float* k = (const float*)d_in[1];
  const float* G = (const float*)d_in[2];
  float* out = (float*)d_out;
  char* ws = (char*)d_ws;

  f16*   qs16   = (f16*)(ws + QS_OFF);
  f16*   gh     = (f16*)(ws + GH_OFF);
  float* gt     = (float*)(ws + GT_OFF);
  u32*   packed = (u32*)(ws + PACKED_OFF);

  // suspect mask in d_out (8M u32 = 32MB << out_size floats); fully
  // rewritten by proj_sign each call; est overwrites d_out afterwards.
  u32* smask = (u32*)d_out;

  prep_qs_kernel<<<2048, 256, 0, stream>>>(q, G, qs16);
  prep_g_kernel<<<128, 256, 0, stream>>>(G, gh, gt);
  proj_sign_kernel<<<8192, 256, 0, stream>>>(k, gh, packed, smask);
  fixup_kernel<<<4096, 256, 0, stream>>>(k, gt, packed, smask);
  est_kernel<<<4096, 256, 0, stream>>>(qs16, packed, out);
}